// Round 6
// baseline (1349.470 us; speedup 1.0000x reference)
//
#include <hip/hip_runtime.h>
#include <hip/hip_bf16.h>

typedef __attribute__((ext_vector_type(8))) short bf16x8;
typedef __attribute__((ext_vector_type(4))) float f32x4;
typedef __attribute__((ext_vector_type(4))) unsigned int u32x4;
typedef __attribute__((ext_vector_type(2))) unsigned int u32x2;

__device__ __forceinline__ unsigned short f2bf(float f) {
    unsigned u = __builtin_bit_cast(unsigned, f);
    u += 0x7FFFu + ((u >> 16) & 1u);   // RNE
    return (unsigned short)(u >> 16);
}

// async global->LDS, 16B per lane: LDS dest = wave-uniform base + lane*16.
__device__ __forceinline__ void async16(const void* g, void* l) {
    __builtin_amdgcn_global_load_lds(
        (const __attribute__((address_space(1))) unsigned int*)g,
        (__attribute__((address_space(3))) unsigned int*)l, 16, 0, 0);
}

template <int N> __device__ __forceinline__ void waitv() {
    if constexpr (N == 8)      asm volatile("s_waitcnt vmcnt(8)" ::: "memory");
    else if constexpr (N == 6) asm volatile("s_waitcnt vmcnt(6)" ::: "memory");
    else if constexpr (N == 4) asm volatile("s_waitcnt vmcnt(4)" ::: "memory");
    else if constexpr (N == 3) asm volatile("s_waitcnt vmcnt(3)" ::: "memory");
    else                       asm volatile("s_waitcnt vmcnt(0)" ::: "memory");
}
#define BARF() do { __builtin_amdgcn_s_barrier(); asm volatile("" ::: "memory"); } while (0)

// two-register lane-group swaps (gfx950): a.hi16grp <-> b.lo16grp etc.
__device__ __forceinline__ void pl32(unsigned &a, unsigned &b) {
    u32x2 r = __builtin_amdgcn_permlane32_swap(a, b, false, false);
    a = r[0]; b = r[1];
}
__device__ __forceinline__ void pl16(unsigned &a, unsigned &b) {
    u32x2 r = __builtin_amdgcn_permlane16_swap(a, b, false, false);
    a = r[0]; b = r[1];
}

__global__ void cvt_f32_bf16(const float* __restrict__ x, unsigned short* __restrict__ y, int n4) {
    const int stride = gridDim.x * blockDim.x;
    for (int i = blockIdx.x * blockDim.x + threadIdx.x; i < n4; i += stride) {
        const float4 v = ((const float4*)x)[i];
        ushort4 o;
        o.x = f2bf(v.x); o.y = f2bf(v.y); o.z = f2bf(v.z); o.w = f2bf(v.w);
        ((ushort4*)y)[i] = o;
    }
}

// merged pre-QKV conversions: hidden->hb, Wq/Wk/Wv->Wcat (one launch).
__global__ void cvt4_f32_bf16(
    const float* __restrict__ h, const float* __restrict__ wq,
    const float* __restrict__ wk, const float* __restrict__ wv,
    unsigned short* __restrict__ hb, unsigned short* __restrict__ wcat)
{
    constexpr int NH = 4194304, NW = 4194304, NK = 131072;   // float4 counts
    constexpr int TOT = NH + NW + NK + NK;
    const int stride = gridDim.x * blockDim.x;
    for (int i = blockIdx.x * blockDim.x + threadIdx.x; i < TOT; i += stride) {
        const float* src; unsigned short* dst; int j;
        if (i < NH)            { src = h;  dst = hb;              j = i; }
        else if (i < NH + NW)  { src = wq; dst = wcat;            j = i - NH; }
        else if (i < NH + NW + NK) { src = wk; dst = wcat + 16777216; j = i - NH - NW; }
        else                   { src = wv; dst = wcat + 17301504; j = i - NH - NW - NK; }
        const float4 v = ((const float4*)src)[j];
        ushort4 o;
        o.x = f2bf(v.x); o.y = f2bf(v.y); o.z = f2bf(v.z); o.w = f2bf(v.w);
        ((ushort4*)dst)[j] = o;
    }
}

// Ring-3 pipelined GEMM, BM=128 (MREP=4), BN=256, BK=32, 512 threads
// (8 waves = 2M x 4N). LDS 3 x 24KB = 73.7KB -> 2 blocks/CU (the R5 ring-4
// version was 96+KB -> 1 block/CU, whole-CU convoy on every barrier).
// Prologue stages 2 tiles; loop: waitv<CALLS> (tile t retired, t+1 in
// flight) -> barrier -> stage t+2 into the slot freed at this barrier ->
// compute t. Counted vmcnt never drains mid-loop. XOR-swizzled LDS with
// pre-swizzled global source (rule #21), setprio around MFMA cluster.
// MODE 0: C = A@Bt^T + b0 as f32 (O-projection).
// MODE 1: fused QKV epilogue; Q is pre-scaled by 1/sqrt(D)*log2(e) so the
//         attention kernel can exp2 scores directly.
template <int MREP, int MODE>
__global__ __launch_bounds__(512, 4) void gemm256(
    const unsigned short* __restrict__ A, const unsigned short* __restrict__ Bt,
    const float* __restrict__ b0, const float* __restrict__ b1, const float* __restrict__ b2,
    void* __restrict__ o0, unsigned short* __restrict__ o1, unsigned short* __restrict__ o2)
{
    constexpr int K = 4096, NT = 128;
    constexpr int ACALLS = MREP / 4;       // 1
    constexpr int CALLS  = ACALLS + 2;     // 3
    constexpr int ASH    = MREP * 1024;    // 4096 shorts
    constexpr int SLOT   = ASH + 8192;     // 12288 shorts = 24 KB
    __shared__ __align__(16) unsigned short lds[3 * SLOT];

    const int tid  = threadIdx.x;
    const int w    = tid >> 6, lane = tid & 63;
    const int l16  = lane & 15, quad = lane >> 4;
    const int wm   = w >> 2, wn = w & 3;

    int bx, by;
    {
        const int wg = (int)blockIdx.x;
        if constexpr (MODE == 1) {         // grid 544 = 17 x * 32 y
            const int wgp = (wg & 7) * 68 + (wg >> 3);
            bx = wgp / 32; by = wgp % 32;
        } else {                           // grid 512 = 16 x * 32 y
            const int wgp = (wg & 7) * 64 + (wg >> 3);
            bx = wgp / 32; by = wgp % 32;
        }
    }
    const int m0 = by * (MREP * 32);
    const int n0 = bx * 256;

    const int srow = lane >> 2;
    const int schk = ((lane & 3) ^ ((lane >> 3) & 3)) * 8;
    const unsigned short* gAs[ACALLS];
#pragma unroll
    for (int c = 0; c < ACALLS; ++c)
        gAs[c] = A + (size_t)(m0 + (w * ACALLS + c) * 16 + srow) * K + schk;
    const unsigned short* gBs[2];
#pragma unroll
    for (int c = 0; c < 2; ++c)
        gBs[c] = Bt + (size_t)(n0 + (w * 2 + c) * 16 + srow) * K + schk;

    const int swz8 = (quad ^ ((l16 >> 1) & 3)) * 8;
    const int aoff = (wm * (MREP * 16) + l16) * 32 + swz8;
    const int boff = ASH + (wn * 64 + l16) * 32 + swz8;

    f32x4 acc[MREP][4] = {};

#define STAGE(OB, tt) do { \
    unsigned short* lb = &lds[(OB)]; \
    _Pragma("unroll") \
    for (int c = 0; c < ACALLS; ++c) \
        async16(gAs[c] + (tt) * 32, lb + (w * ACALLS + c) * 512); \
    _Pragma("unroll") \
    for (int c = 0; c < 2; ++c) \
        async16(gBs[c] + (tt) * 32, lb + ASH + (w * 2 + c) * 512); \
} while (0)

#define BODY(OB) do { \
    const unsigned short* lb = &lds[(OB)]; \
    bf16x8 af[MREP], bfr[4]; \
    _Pragma("unroll") \
    for (int i = 0; i < MREP; ++i) af[i] = *(const bf16x8*)(lb + aoff + i * 512); \
    _Pragma("unroll") \
    for (int j = 0; j < 4; ++j)    bfr[j] = *(const bf16x8*)(lb + boff + j * 512); \
    __builtin_amdgcn_s_setprio(1); \
    _Pragma("unroll") \
    for (int i = 0; i < MREP; ++i) { \
        _Pragma("unroll") \
        for (int j = 0; j < 4; ++j) \
            acc[i][j] = __builtin_amdgcn_mfma_f32_16x16x32_bf16(af[i], bfr[j], acc[i][j], 0, 0, 0); \
    } \
    __builtin_amdgcn_s_setprio(0); \
} while (0)

    STAGE(0, 0); STAGE(SLOT, 1);
    int oa = 0, ob = SLOT, oc = 2 * SLOT;
    for (int t = 0; t < NT - 2; ++t) {
        waitv<CALLS>();      // tile t retired; tile t+1 stays in flight
        BARF();              // slot oc (tile t-1) free for all waves
        STAGE(oc, t + 2);
        BODY(oa);
        const int tmp = oa; oa = ob; ob = oc; oc = tmp;
    }
    waitv<CALLS>(); BARF(); BODY(oa);    // tile NT-2
    waitv<0>();     BARF(); BODY(ob);    // tile NT-1

#undef STAGE
#undef BODY

    if constexpr (MODE == 0) {
        float* C = (float*)o0;
#pragma unroll
        for (int j = 0; j < 4; ++j) {
            const int n = n0 + wn * 64 + j * 16 + l16;
            const float bb = b0[n];
#pragma unroll
            for (int i = 0; i < MREP; ++i) {
                const int mb = m0 + wm * (MREP * 16) + i * 16 + quad * 4;
#pragma unroll
                for (int r = 0; r < 4; ++r)
                    C[(size_t)(mb + r) * 4096 + n] = acc[i][j][r] + bb;
            }
        }
    } else {
        constexpr float CSC = 0.0883883476483184f * 1.4426950408889634f;  // 1/sqrt(D)*log2(e)
        unsigned short* q_out = (unsigned short*)o0;
        const int nw0 = n0 + wn * 64;
        if (nw0 < 4096) {                       // Q region (pre-scaled by CSC)
#pragma unroll
            for (int j = 0; j < 4; ++j) {
                const int n = nw0 + j * 16 + l16;
                const float bb = b0[n];
#pragma unroll
                for (int i = 0; i < MREP; ++i) {
                    const int mb = m0 + wm * (MREP * 16) + i * 16 + quad * 4;
#pragma unroll
                    for (int r = 0; r < 4; ++r)
                        q_out[(size_t)(mb + r) * 4096 + n] = f2bf((acc[i][j][r] + bb) * CSC);
                }
            }
        } else if (nw0 < 4224) {                // K region
#pragma unroll
            for (int j = 0; j < 4; ++j) {
                const int d = nw0 - 4096 + j * 16 + l16;
                const float bb = b1[d];
#pragma unroll
                for (int i = 0; i < MREP; ++i) {
                    const int mb = m0 + wm * (MREP * 16) + i * 16 + quad * 4;
#pragma unroll
                    for (int r = 0; r < 4; ++r)
                        o1[(size_t)(mb + r) * 128 + d] = f2bf(acc[i][j][r] + bb);
                }
            }
        } else {                                // V region -> vT[b][d][s]
#pragma unroll
            for (int j = 0; j < 4; ++j) {
                const int d = nw0 - 4224 + j * 16 + l16;
                const float bb = b2[d];
#pragma unroll
                for (int i = 0; i < MREP; ++i) {
                    const int mb = m0 + wm * (MREP * 16) + i * 16 + quad * 4;
                    ushort4 o;
                    o.x = f2bf(acc[i][j][0] + bb);
                    o.y = f2bf(acc[i][j][1] + bb);
                    o.z = f2bf(acc[i][j][2] + bb);
                    o.w = f2bf(acc[i][j][3] + bb);
                    *(ushort4*)(o2 + (size_t)((mb >> 11) * 128 + d) * 2048 + (mb & 2047)) = o;
                }
            }
        }
    }
}

// Flash MQA, fixed-max softmax, T12 in-register P path + ring-2 pipelined
// KV staging (KVBLK=32). Q arrives pre-scaled by 1/sqrt(D)*log2(e), so
// softmax is exp2(sf) directly (16 fewer v_mul per tile per wave).
// LDS trimmed to exactly 32 KB (2x16KB ring; epilogue in two 64-row passes
// aliasing one ring slot) -> 5 blocks/CU. grid 1024.
__global__ __launch_bounds__(256, 5) void attn_mqa(
    const unsigned short* __restrict__ Q,
    const unsigned short* __restrict__ Kb,
    const unsigned short* __restrict__ vT,
    unsigned short* __restrict__ scr)
{
    constexpr int S = 2048, D = 128, H = 4096;

    __shared__ __align__(16) unsigned short lds[16384];
    // ring-2, buffer (t&1)*8192: K chunks c*512 (c<8), V chunks 4096+c*512
    // epilogue (2 passes): Ost[64][pitch 136] aliases [0,8704)

    const int tid = threadIdx.x;
    const int w = tid >> 6, lane = tid & 63;
    const int l16 = lane & 15, quad = lane >> 4;
    const int qb = blockIdx.x & 15;
    const int h  = (blockIdx.x >> 4) & 31;
    const int b  = blockIdx.x >> 9;
    const int q0 = qb * 128;

    bf16x8 qf[2][4];
#pragma unroll
    for (int mi = 0; mi < 2; ++mi)
#pragma unroll
        for (int ks = 0; ks < 4; ++ks)
            qf[mi][ks] = *(const bf16x8*)(Q + (size_t)(b * S + q0 + w * 32 + mi * 16 + l16) * H
                                            + h * D + ks * 32 + quad * 8);

    f32x4 Oa[2][8] = {};
    float l_run[2] = {};

    const unsigned short* gK = Kb + (size_t)(b * S + l16) * D + quad * 8;
    const unsigned short* gV = vT + (size_t)(b * 128 + l16) * 2048 + quad * 8;

    // wave w stages chunks {w*2, w*2+1} for both K and V: 4 async16/wave/tile
#define ASTAGE(tt) do { \
    unsigned short* buf = &lds[((tt) & 1) * 8192]; \
    const int kv0s = (tt) * 32; \
    _Pragma("unroll") \
    for (int c2 = 0; c2 < 2; ++c2) { \
        const int c = w * 2 + c2; \
        async16(gK + (size_t)(kv0s + (c >> 2) * 16) * D + (c & 3) * 32, buf + c * 512); \
        async16(gV + (size_t)(c * 16) * 2048 + kv0s, buf + 4096 + c * 512); \
    } \
} while (0)

    ASTAGE(0);
    for (int t = 0; t < 64; ++t) {
        waitv<0>();          // own 4 loads for tile t (issued one phase ago)
        BARF();              // all waves' loads done; buffer (t+1)&1 free
        if (t < 63) ASTAGE(t + 1);

        const unsigned short* Kl = &lds[(t & 1) * 8192];
        const unsigned short* Vl = Kl + 4096;

        // S^T = K Q^T : lane holds P[kv = ct*16+quad*4+i][q = l16] per mi
        f32x4 sf[2][2] = {};
#pragma unroll
        for (int ct = 0; ct < 2; ++ct)
#pragma unroll
            for (int ks = 0; ks < 4; ++ks) {
                const bf16x8 kf = *(const bf16x8*)&Kl[(ct * 4 + ks) * 512 + lane * 8];
#pragma unroll
                for (int mi = 0; mi < 2; ++mi)
                    sf[mi][ct] = __builtin_amdgcn_mfma_f32_16x16x32_bf16(kf, qf[mi][ks], sf[mi][ct], 0, 0, 0);
            }

        // in-register softmax + A-fragment assembly (cvt_pk + permlane swaps)
        bf16x8 pa[2];
#pragma unroll
        for (int mi = 0; mi < 2; ++mi) {
            unsigned cw[2][2];
#pragma unroll
            for (int ct = 0; ct < 2; ++ct) {
                const float p0 = exp2f(sf[mi][ct][0]);
                const float p1 = exp2f(sf[mi][ct][1]);
                const float p2 = exp2f(sf[mi][ct][2]);
                const float p3 = exp2f(sf[mi][ct][3]);
                l_run[mi] += (p0 + p1) + (p2 + p3);
                asm("v_cvt_pk_bf16_f32 %0, %1, %2" : "=v"(cw[ct][0]) : "v"(p0), "v"(p1));
                asm("v_cvt_pk_bf16_f32 %0, %1, %2" : "=v"(cw[ct][1]) : "v"(p2), "v"(p3));
            }
            unsigned c0 = cw[0][0], c1 = cw[0][1];
            unsigned d0 = cw[1][0], d1 = cw[1][1];
            pl32(c0, d0); pl16(c0, d0);   // -> words 0/2: kv = quad*8 + {0..3},{4..7} lo
            pl32(c1, d1); pl16(c1, d1);
            u32x4 t4; t4[0] = c0; t4[1] = c1; t4[2] = d0; t4[3] = d1;
            pa[mi] = __builtin_bit_cast(bf16x8, t4);
        }

        // O += P V  (pa in A-fragment layout: q=l16, kv=quad*8+j)
        __builtin_amdgcn_s_setprio(1);
#pragma unroll
        for (int nt = 0; nt < 8; ++nt) {
            const bf16x8 vf = *(const bf16x8*)&Vl[nt * 512 + lane * 8];
#pragma unroll
            for (int mi = 0; mi < 2; ++mi)
                Oa[mi][nt] = __builtin_amdgcn_mfma_f32_16x16x32_bf16(pa[mi], vf, Oa[mi][nt], 0, 0, 0);
        }
        __builtin_amdgcn_s_setprio(0);
    }
#undef ASTAGE

    // l lives per-lane for q=l16, kv-partial per quad: all-reduce over quads,
    // then redistribute to PV output layout (q = quad*4 + i).
    float iv[2][4];
#pragma unroll
    for (int mi = 0; mi < 2; ++mi) {
        float l = l_run[mi];
        l += __shfl_xor(l, 16);
        l += __shfl_xor(l, 32);
        const float linv = 1.f / l;
#pragma unroll
        for (int i = 0; i < 4; ++i)
            iv[mi][i] = __shfl(linv, quad * 4 + i);
    }

    // two-pass epilogue (64 d-rows per pass) through an 8704-short buffer
#pragma unroll
    for (int p = 0; p < 2; ++p) {
        __syncthreads();
#pragma unroll
        for (int mi = 0; mi < 2; ++mi)
#pragma unroll
            for (int nt = 0; nt < 4; ++nt)
#pragma unroll
                for (int i = 0; i < 4; ++i)
                    lds[(nt * 16 + l16) * 136 + w * 32 + mi * 16 + quad * 4 + i] =
                        f2bf(Oa[mi][p * 4 + nt][i] * iv[mi][i]);
        __syncthreads();
        // scrambled coalesced store: scr[b][h*64 + d/2][(d&1)*2048 + q]
        const int dl = tid >> 2, qq = tid & 3;
        const int d = p * 64 + dl;
        unsigned short* op = scr + (size_t)(b * S + h * 64 + (d >> 1)) * H + (d & 1) * 2048 + q0 + qq * 32;
#pragma unroll
        for (int j = 0; j < 4; ++j)
            *(int4*)(op + j * 8) = *(const int4*)&lds[dl * 136 + qq * 32 + j * 8];
    }
}

extern "C" void kernel_launch(void* const* d_in, const int* in_sizes, int n_in,
                              void* d_out, int out_size, void* d_ws, size_t ws_size,
                              hipStream_t stream) {
    (void)in_sizes; (void)n_in; (void)out_size; (void)ws_size;
    const float* hidden = (const float*)d_in[0];
    const float* Wq = (const float*)d_in[1];
    const float* bq = (const float*)d_in[2];
    const float* Wk = (const float*)d_in[3];
    const float* bk = (const float*)d_in[4];
    const float* Wv = (const float*)d_in[5];
    const float* bv = (const float*)d_in[6];
    const float* Wo = (const float*)d_in[7];
    const float* bo = (const float*)d_in[8];

    char* ws = (char*)d_ws;
    const size_t MB = 1048576;
    unsigned short* hb   = (unsigned short*)(ws);                 // 32 MB; scr aliases after attn input phase
    unsigned short* scr  = hb;                                    // hb dead once QKV gemm completes
    unsigned short* Wcat = (unsigned short*)(ws + 32 * MB);       // 36 MB: [Wq;Wk;Wv]; Wo aliases after QKV
    unsigned short* Wob  = Wcat;
    unsigned short* q_b  = (unsigned short*)(ws + 68 * MB);       // 32 MB
    unsigned short* k_b  = (unsigned short*)(ws + 100 * MB);      // 1 MB
    unsigned short* vT   = (unsigned short*)(ws + 101 * MB);      // 1 MB

    cvt4_f32_bf16<<<2048, 256, 0, stream>>>(hidden, Wq, Wk, Wv, hb, Wcat);

    gemm256<4, 1><<<dim3(544), 512, 0, stream>>>(hb, Wcat, bq, bk, bv,
                                                 (void*)q_b, k_b, vT);
    cvt_f32_bf16<<<1024, 256, 0, stream>>>(Wo, Wob, 16777216 / 4);   // Wcat region dead after QKV
    attn_mqa<<<1024, 256, 0, stream>>>(q_b, k_b, vT, scr);           // scr aliases hb (dead)
    gemm256<4, 0><<<dim3(512), 512, 0, stream>>>(scr, Wob, bo, nullptr, nullptr,
                                                 (void*)d_out, nullptr, nullptr);
}

// Round 7
// 755.806 us; speedup vs baseline: 1.7855x; 1.7855x over previous
//
#include <hip/hip_runtime.h>
#include <hip/hip_bf16.h>

typedef __attribute__((ext_vector_type(8))) short bf16x8;
typedef __attribute__((ext_vector_type(4))) float f32x4;
typedef __attribute__((ext_vector_type(4))) unsigned int u32x4;
typedef __attribute__((ext_vector_type(2))) unsigned int u32x2;

__device__ __forceinline__ unsigned short f2bf(float f) {
    unsigned u = __builtin_bit_cast(unsigned, f);
    u += 0x7FFFu + ((u >> 16) & 1u);   // RNE
    return (unsigned short)(u >> 16);
}

// async global->LDS, 16B per lane: LDS dest = wave-uniform base + lane*16.
__device__ __forceinline__ void async16(const void* g, void* l) {
    __builtin_amdgcn_global_load_lds(
        (const __attribute__((address_space(1))) unsigned int*)g,
        (__attribute__((address_space(3))) unsigned int*)l, 16, 0, 0);
}

template <int N> __device__ __forceinline__ void waitv() {
    if constexpr (N == 8)      asm volatile("s_waitcnt vmcnt(8)" ::: "memory");
    else if constexpr (N == 6) asm volatile("s_waitcnt vmcnt(6)" ::: "memory");
    else if constexpr (N == 4) asm volatile("s_waitcnt vmcnt(4)" ::: "memory");
    else if constexpr (N == 3) asm volatile("s_waitcnt vmcnt(3)" ::: "memory");
    else                       asm volatile("s_waitcnt vmcnt(0)" ::: "memory");
}
#define BARF() do { __builtin_amdgcn_s_barrier(); asm volatile("" ::: "memory"); } while (0)

// two-register lane-group swaps (gfx950): a.hi16grp <-> b.lo16grp etc.
__device__ __forceinline__ void pl32(unsigned &a, unsigned &b) {
    u32x2 r = __builtin_amdgcn_permlane32_swap(a, b, false, false);
    a = r[0]; b = r[1];
}
__device__ __forceinline__ void pl16(unsigned &a, unsigned &b) {
    u32x2 r = __builtin_amdgcn_permlane16_swap(a, b, false, false);
    a = r[0]; b = r[1];
}

__global__ void cvt_f32_bf16(const float* __restrict__ x, unsigned short* __restrict__ y, int n4) {
    const int stride = gridDim.x * blockDim.x;
    for (int i = blockIdx.x * blockDim.x + threadIdx.x; i < n4; i += stride) {
        const float4 v = ((const float4*)x)[i];
        ushort4 o;
        o.x = f2bf(v.x); o.y = f2bf(v.y); o.z = f2bf(v.z); o.w = f2bf(v.w);
        ((ushort4*)y)[i] = o;
    }
}

// merged pre-QKV conversions: hidden->hb, Wq/Wk/Wv->Wcat (one launch).
__global__ void cvt4_f32_bf16(
    const float* __restrict__ h, const float* __restrict__ wq,
    const float* __restrict__ wk, const float* __restrict__ wv,
    unsigned short* __restrict__ hb, unsigned short* __restrict__ wcat)
{
    constexpr int NH = 4194304, NW = 4194304, NK = 131072;   // float4 counts
    constexpr int TOT = NH + NW + NK + NK;
    const int stride = gridDim.x * blockDim.x;
    for (int i = blockIdx.x * blockDim.x + threadIdx.x; i < TOT; i += stride) {
        const float* src; unsigned short* dst; int j;
        if (i < NH)            { src = h;  dst = hb;              j = i; }
        else if (i < NH + NW)  { src = wq; dst = wcat;            j = i - NH; }
        else if (i < NH + NW + NK) { src = wk; dst = wcat + 16777216; j = i - NH - NW; }
        else                   { src = wv; dst = wcat + 17301504; j = i - NH - NW - NK; }
        const float4 v = ((const float4*)src)[j];
        ushort4 o;
        o.x = f2bf(v.x); o.y = f2bf(v.y); o.z = f2bf(v.z); o.w = f2bf(v.w);
        ((ushort4*)dst)[j] = o;
    }
}

// Ring-3 pipelined GEMM, BM=128 (MREP=4), BN=256, BK=32, 512 threads
// (8 waves = 2M x 4N). LDS 3 x 24KB = 73.7KB -> 2 blocks/CU.
// Prologue stages 2 tiles; loop: waitv<CALLS> (tile t retired, t+1 in
// flight) -> barrier -> stage t+2 into the slot freed at this barrier ->
// compute t. Counted vmcnt never drains mid-loop. XOR-swizzled LDS with
// pre-swizzled global source (rule #21), setprio around MFMA cluster.
// MODE 0: C = A@Bt^T + b0 as f32 (O-projection).
// MODE 1: fused QKV epilogue; Q is pre-scaled by 1/sqrt(D)*log2(e) so the
//         attention kernel can exp2 scores directly.
template <int MREP, int MODE>
__global__ __launch_bounds__(512, 4) void gemm256(
    const unsigned short* __restrict__ A, const unsigned short* __restrict__ Bt,
    const float* __restrict__ b0, const float* __restrict__ b1, const float* __restrict__ b2,
    void* __restrict__ o0, unsigned short* __restrict__ o1, unsigned short* __restrict__ o2)
{
    constexpr int K = 4096, NT = 128;
    constexpr int ACALLS = MREP / 4;       // 1
    constexpr int CALLS  = ACALLS + 2;     // 3
    constexpr int ASH    = MREP * 1024;    // 4096 shorts
    constexpr int SLOT   = ASH + 8192;     // 12288 shorts = 24 KB
    __shared__ __align__(16) unsigned short lds[3 * SLOT];

    const int tid  = threadIdx.x;
    const int w    = tid >> 6, lane = tid & 63;
    const int l16  = lane & 15, quad = lane >> 4;
    const int wm   = w >> 2, wn = w & 3;

    int bx, by;
    {
        const int wg = (int)blockIdx.x;
        if constexpr (MODE == 1) {         // grid 544 = 17 x * 32 y
            const int wgp = (wg & 7) * 68 + (wg >> 3);
            bx = wgp / 32; by = wgp % 32;
        } else {                           // grid 512 = 16 x * 32 y
            const int wgp = (wg & 7) * 64 + (wg >> 3);
            bx = wgp / 32; by = wgp % 32;
        }
    }
    const int m0 = by * (MREP * 32);
    const int n0 = bx * 256;

    const int srow = lane >> 2;
    const int schk = ((lane & 3) ^ ((lane >> 3) & 3)) * 8;
    const unsigned short* gAs[ACALLS];
#pragma unroll
    for (int c = 0; c < ACALLS; ++c)
        gAs[c] = A + (size_t)(m0 + (w * ACALLS + c) * 16 + srow) * K + schk;
    const unsigned short* gBs[2];
#pragma unroll
    for (int c = 0; c < 2; ++c)
        gBs[c] = Bt + (size_t)(n0 + (w * 2 + c) * 16 + srow) * K + schk;

    const int swz8 = (quad ^ ((l16 >> 1) & 3)) * 8;
    const int aoff = (wm * (MREP * 16) + l16) * 32 + swz8;
    const int boff = ASH + (wn * 64 + l16) * 32 + swz8;

    f32x4 acc[MREP][4] = {};

#define STAGE(OB, tt) do { \
    unsigned short* lb = &lds[(OB)]; \
    _Pragma("unroll") \
    for (int c = 0; c < ACALLS; ++c) \
        async16(gAs[c] + (tt) * 32, lb + (w * ACALLS + c) * 512); \
    _Pragma("unroll") \
    for (int c = 0; c < 2; ++c) \
        async16(gBs[c] + (tt) * 32, lb + ASH + (w * 2 + c) * 512); \
} while (0)

#define BODY(OB) do { \
    const unsigned short* lb = &lds[(OB)]; \
    bf16x8 af[MREP], bfr[4]; \
    _Pragma("unroll") \
    for (int i = 0; i < MREP; ++i) af[i] = *(const bf16x8*)(lb + aoff + i * 512); \
    _Pragma("unroll") \
    for (int j = 0; j < 4; ++j)    bfr[j] = *(const bf16x8*)(lb + boff + j * 512); \
    __builtin_amdgcn_s_setprio(1); \
    _Pragma("unroll") \
    for (int i = 0; i < MREP; ++i) { \
        _Pragma("unroll") \
        for (int j = 0; j < 4; ++j) \
            acc[i][j] = __builtin_amdgcn_mfma_f32_16x16x32_bf16(af[i], bfr[j], acc[i][j], 0, 0, 0); \
    } \
    __builtin_amdgcn_s_setprio(0); \
} while (0)

    STAGE(0, 0); STAGE(SLOT, 1);
    int oa = 0, ob = SLOT, oc = 2 * SLOT;
    for (int t = 0; t < NT - 2; ++t) {
        waitv<CALLS>();      // tile t retired; tile t+1 stays in flight
        BARF();              // slot oc (tile t-1) free for all waves
        STAGE(oc, t + 2);
        BODY(oa);
        const int tmp = oa; oa = ob; ob = oc; oc = tmp;
    }
    waitv<CALLS>(); BARF(); BODY(oa);    // tile NT-2
    waitv<0>();     BARF(); BODY(ob);    // tile NT-1

#undef STAGE
#undef BODY

    if constexpr (MODE == 0) {
        float* C = (float*)o0;
#pragma unroll
        for (int j = 0; j < 4; ++j) {
            const int n = n0 + wn * 64 + j * 16 + l16;
            const float bb = b0[n];
#pragma unroll
            for (int i = 0; i < MREP; ++i) {
                const int mb = m0 + wm * (MREP * 16) + i * 16 + quad * 4;
#pragma unroll
                for (int r = 0; r < 4; ++r)
                    C[(size_t)(mb + r) * 4096 + n] = acc[i][j][r] + bb;
            }
        }
    } else {
        constexpr float CSC = 0.0883883476483184f * 1.4426950408889634f;  // 1/sqrt(D)*log2(e)
        unsigned short* q_out = (unsigned short*)o0;
        const int nw0 = n0 + wn * 64;
        if (nw0 < 4096) {                       // Q region (pre-scaled by CSC)
#pragma unroll
            for (int j = 0; j < 4; ++j) {
                const int n = nw0 + j * 16 + l16;
                const float bb = b0[n];
#pragma unroll
                for (int i = 0; i < MREP; ++i) {
                    const int mb = m0 + wm * (MREP * 16) + i * 16 + quad * 4;
#pragma unroll
                    for (int r = 0; r < 4; ++r)
                        q_out[(size_t)(mb + r) * 4096 + n] = f2bf((acc[i][j][r] + bb) * CSC);
                }
            }
        } else if (nw0 < 4224) {                // K region
#pragma unroll
            for (int j = 0; j < 4; ++j) {
                const int d = nw0 - 4096 + j * 16 + l16;
                const float bb = b1[d];
#pragma unroll
                for (int i = 0; i < MREP; ++i) {
                    const int mb = m0 + wm * (MREP * 16) + i * 16 + quad * 4;
#pragma unroll
                    for (int r = 0; r < 4; ++r)
                        o1[(size_t)(mb + r) * 128 + d] = f2bf(acc[i][j][r] + bb);
                }
            }
        } else {                                // V region -> vT[b][d][s]
#pragma unroll
            for (int j = 0; j < 4; ++j) {
                const int d = nw0 - 4224 + j * 16 + l16;
                const float bb = b2[d];
#pragma unroll
                for (int i = 0; i < MREP; ++i) {
                    const int mb = m0 + wm * (MREP * 16) + i * 16 + quad * 4;
                    ushort4 o;
                    o.x = f2bf(acc[i][j][0] + bb);
                    o.y = f2bf(acc[i][j][1] + bb);
                    o.z = f2bf(acc[i][j][2] + bb);
                    o.w = f2bf(acc[i][j][3] + bb);
                    *(ushort4*)(o2 + (size_t)((mb >> 11) * 128 + d) * 2048 + (mb & 2047)) = o;
                }
            }
        }
    }
}

// Flash MQA, fixed-max softmax, T12 in-register P path + ring-2 pipelined
// KV staging (KVBLK=32). Q arrives pre-scaled by 1/sqrt(D)*log2(e), so
// softmax is exp2(sf) directly. LDS exactly 32 KB (2x16KB ring; epilogue
// in two 64-row passes aliasing one ring slot).
// __launch_bounds__(256,4): reg budget 128 = 64 acc (unified file!) + 64
// arch; (256,5) in R6 forced ~102 and spilled 3.6 GB/dispatch to scratch.
// Achieved occupancy = min(LDS 5, VGPR 8) = 5 blocks/CU. grid 1024.
__global__ __launch_bounds__(256, 4) void attn_mqa(
    const unsigned short* __restrict__ Q,
    const unsigned short* __restrict__ Kb,
    const unsigned short* __restrict__ vT,
    unsigned short* __restrict__ scr)
{
    constexpr int S = 2048, D = 128, H = 4096;

    __shared__ __align__(16) unsigned short lds[16384];
    // ring-2, buffer (t&1)*8192: K chunks c*512 (c<8), V chunks 4096+c*512
    // epilogue (2 passes): Ost[64][pitch 136] aliases [0,8704)

    const int tid = threadIdx.x;
    const int w = tid >> 6, lane = tid & 63;
    const int l16 = lane & 15, quad = lane >> 4;
    const int qb = blockIdx.x & 15;
    const int h  = (blockIdx.x >> 4) & 31;
    const int b  = blockIdx.x >> 9;
    const int q0 = qb * 128;

    bf16x8 qf[2][4];
#pragma unroll
    for (int mi = 0; mi < 2; ++mi)
#pragma unroll
        for (int ks = 0; ks < 4; ++ks)
            qf[mi][ks] = *(const bf16x8*)(Q + (size_t)(b * S + q0 + w * 32 + mi * 16 + l16) * H
                                            + h * D + ks * 32 + quad * 8);

    f32x4 Oa[2][8] = {};
    float l_run[2] = {};

    const unsigned short* gK = Kb + (size_t)(b * S + l16) * D + quad * 8;
    const unsigned short* gV = vT + (size_t)(b * 128 + l16) * 2048 + quad * 8;

    // wave w stages chunks {w*2, w*2+1} for both K and V: 4 async16/wave/tile
#define ASTAGE(tt) do { \
    unsigned short* buf = &lds[((tt) & 1) * 8192]; \
    const int kv0s = (tt) * 32; \
    _Pragma("unroll") \
    for (int c2 = 0; c2 < 2; ++c2) { \
        const int c = w * 2 + c2; \
        async16(gK + (size_t)(kv0s + (c >> 2) * 16) * D + (c & 3) * 32, buf + c * 512); \
        async16(gV + (size_t)(c * 16) * 2048 + kv0s, buf + 4096 + c * 512); \
    } \
} while (0)

    ASTAGE(0);
    for (int t = 0; t < 64; ++t) {
        waitv<0>();          // own 4 loads for tile t (issued one phase ago)
        BARF();              // all waves' loads done; buffer (t+1)&1 free
        if (t < 63) ASTAGE(t + 1);

        const unsigned short* Kl = &lds[(t & 1) * 8192];
        const unsigned short* Vl = Kl + 4096;

        // S^T = K Q^T : lane holds P[kv = ct*16+quad*4+i][q = l16] per mi
        f32x4 sf[2][2] = {};
#pragma unroll
        for (int ct = 0; ct < 2; ++ct)
#pragma unroll
            for (int ks = 0; ks < 4; ++ks) {
                const bf16x8 kf = *(const bf16x8*)&Kl[(ct * 4 + ks) * 512 + lane * 8];
#pragma unroll
                for (int mi = 0; mi < 2; ++mi)
                    sf[mi][ct] = __builtin_amdgcn_mfma_f32_16x16x32_bf16(kf, qf[mi][ks], sf[mi][ct], 0, 0, 0);
            }

        // in-register softmax + A-fragment assembly (cvt_pk + permlane swaps)
        bf16x8 pa[2];
#pragma unroll
        for (int mi = 0; mi < 2; ++mi) {
            unsigned cw[2][2];
#pragma unroll
            for (int ct = 0; ct < 2; ++ct) {
                const float p0 = exp2f(sf[mi][ct][0]);
                const float p1 = exp2f(sf[mi][ct][1]);
                const float p2 = exp2f(sf[mi][ct][2]);
                const float p3 = exp2f(sf[mi][ct][3]);
                l_run[mi] += (p0 + p1) + (p2 + p3);
                asm("v_cvt_pk_bf16_f32 %0, %1, %2" : "=v"(cw[ct][0]) : "v"(p0), "v"(p1));
                asm("v_cvt_pk_bf16_f32 %0, %1, %2" : "=v"(cw[ct][1]) : "v"(p2), "v"(p3));
            }
            unsigned c0 = cw[0][0], c1 = cw[0][1];
            unsigned d0 = cw[1][0], d1 = cw[1][1];
            pl32(c0, d0); pl16(c0, d0);   // -> words 0/2: kv = quad*8 + {0..3},{4..7} lo
            pl32(c1, d1); pl16(c1, d1);
            u32x4 t4; t4[0] = c0; t4[1] = c1; t4[2] = d0; t4[3] = d1;
            pa[mi] = __builtin_bit_cast(bf16x8, t4);
        }

        // O += P V  (pa in A-fragment layout: q=l16, kv=quad*8+j)
        __builtin_amdgcn_s_setprio(1);
#pragma unroll
        for (int nt = 0; nt < 8; ++nt) {
            const bf16x8 vf = *(const bf16x8*)&Vl[nt * 512 + lane * 8];
#pragma unroll
            for (int mi = 0; mi < 2; ++mi)
                Oa[mi][nt] = __builtin_amdgcn_mfma_f32_16x16x32_bf16(pa[mi], vf, Oa[mi][nt], 0, 0, 0);
        }
        __builtin_amdgcn_s_setprio(0);
    }
#undef ASTAGE

    // l lives per-lane for q=l16, kv-partial per quad: all-reduce over quads,
    // then redistribute to PV output layout (q = quad*4 + i).
    float iv[2][4];
#pragma unroll
    for (int mi = 0; mi < 2; ++mi) {
        float l = l_run[mi];
        l += __shfl_xor(l, 16);
        l += __shfl_xor(l, 32);
        const float linv = 1.f / l;
#pragma unroll
        for (int i = 0; i < 4; ++i)
            iv[mi][i] = __shfl(linv, quad * 4 + i);
    }

    // two-pass epilogue (64 d-rows per pass) through an 8704-short buffer
#pragma unroll
    for (int p = 0; p < 2; ++p) {
        __syncthreads();
#pragma unroll
        for (int mi = 0; mi < 2; ++mi)
#pragma unroll
            for (int nt = 0; nt < 4; ++nt)
#pragma unroll
                for (int i = 0; i < 4; ++i)
                    lds[(nt * 16 + l16) * 136 + w * 32 + mi * 16 + quad * 4 + i] =
                        f2bf(Oa[mi][p * 4 + nt][i] * iv[mi][i]);
        __syncthreads();
        // scrambled coalesced store: scr[b][h*64 + d/2][(d&1)*2048 + q]
        const int dl = tid >> 2, qq = tid & 3;
        const int d = p * 64 + dl;
        unsigned short* op = scr + (size_t)(b * S + h * 64 + (d >> 1)) * H + (d & 1) * 2048 + q0 + qq * 32;
#pragma unroll
        for (int j = 0; j < 4; ++j)
            *(int4*)(op + j * 8) = *(const int4*)&lds[dl * 136 + qq * 32 + j * 8];
    }
}

extern "C" void kernel_launch(void* const* d_in, const int* in_sizes, int n_in,
                              void* d_out, int out_size, void* d_ws, size_t ws_size,
                              hipStream_t stream) {
    (void)in_sizes; (void)n_in; (void)out_size; (void)ws_size;
    const float* hidden = (const float*)d_in[0];
    const float* Wq = (const float*)d_in[1];
    const float* bq = (const float*)d_in[2];
    const float* Wk = (const float*)d_in[3];
    const float* bk = (const float*)d_in[4];
    const float* Wv = (const float*)d_in[5];
    const float* bv = (const float*)d_in[6];
    const float* Wo = (const float*)d_in[7];
    const float* bo = (const float*)d_in[8];

    char* ws = (char*)d_ws;
    const size_t MB = 1048576;
    unsigned short* hb   = (unsigned short*)(ws);                 // 32 MB; scr aliases after attn input phase
    unsigned short* scr  = hb;                                    // hb dead once QKV gemm completes
    unsigned short* Wcat = (unsigned short*)(ws + 32 * MB);       // 36 MB: [Wq;Wk;Wv]; Wo aliases after QKV
    unsigned short* Wob  = Wcat;
    unsigned short* q_b  = (unsigned short*)(ws + 68 * MB);       // 32 MB
    unsigned short* k_b  = (unsigned short*)(ws + 100 * MB);      // 1 MB
    unsigned short* vT   = (unsigned short*)(ws + 101 * MB);      // 1 MB

    cvt4_f32_bf16<<<2048, 256, 0, stream>>>(hidden, Wq, Wk, Wv, hb, Wcat);

    gemm256<4, 1><<<dim3(544), 512, 0, stream>>>(hb, Wcat, bq, bk, bv,
                                                 (void*)q_b, k_b, vT);
    cvt_f32_bf16<<<1024, 256, 0, stream>>>(Wo, Wob, 16777216 / 4);   // Wcat region dead after QKV
    attn_mqa<<<1024, 256, 0, stream>>>(q_b, k_b, vT, scr);           // scr aliases hb (dead)
    gemm256<4, 0><<<dim3(512), 512, 0, stream>>>(scr, Wob, bo, nullptr, nullptr,
                                                 (void*)d_out, nullptr, nullptr);
}